// Round 9
// baseline (209.372 us; speedup 1.0000x reference)
//
#include <hip/hip_runtime.h>

#define B_   4
#define H_   8
#define M_   2048
#define D_   512
#define DH_  64

typedef short  bf16x8 __attribute__((ext_vector_type(8)));
typedef short  bf16x4 __attribute__((ext_vector_type(4)));
typedef float  f32x4  __attribute__((ext_vector_type(4)));
typedef unsigned short u16x4 __attribute__((ext_vector_type(4)));
typedef unsigned int   u32x2 __attribute__((ext_vector_type(2)));

#define EXPC 0.18033688011112042f   /* log2(e)/8 : exp(s/8) == exp2(s*EXPC) */

static __device__ __forceinline__ unsigned short f2bf(float f) {
  unsigned u = __float_as_uint(f);
  u += 0x7fffu + ((u >> 16) & 1u);
  return (unsigned short)(u >> 16);
}

// one instruction: [bf16(lo), bf16(hi)] packed into a u32 (RNE)
static __device__ __forceinline__ unsigned cvtpk(float lo, float hi) {
  unsigned r;
  asm("v_cvt_pk_bf16_f32 %0, %1, %2" : "=v"(r) : "v"(lo), "v"(hi));
  return r;
}

// PV matrix op: D = A(4 bf16, d-rows) x B(4 bf16, n-k) + C. ISA cdna4 §10.
static __device__ __forceinline__ f32x4 mfma16(bf16x4 a, bf16x4 b, f32x4 c) {
  asm("v_mfma_f32_16x16x16_bf16 %0, %1, %2, %0" : "+v"(c) : "v"(a), "v"(b));
  return c;
}

static __device__ __forceinline__ int swz128(int row, int byteoff) {
  return row * 128 + (byteoff ^ ((row & 7) << 4));
}

// async global->LDS, 16B per lane, LDS dest = wave-uniform base + lane*16
static __device__ __forceinline__ void glds16(const void* g, void* l) {
  __builtin_amdgcn_global_load_lds(
      (const __attribute__((address_space(1))) unsigned*)g,
      (__attribute__((address_space(3))) unsigned*)l, 16, 0, 0);
}

// stage a 128-row x 128-byte tile (16KB) into LDS in swz128 layout
static __device__ __forceinline__ void stage_tile(
    const char* g0, size_t rstride, char* lds, int t) {
  const int r0 = t >> 3, c0 = t & 7;
  const char* src = g0 + (size_t)r0 * rstride + ((c0 ^ (r0 & 7)) << 4);
  char* dst = lds + ((t & 192) << 4);
  #pragma unroll
  for (int c = 0; c < 4; ++c)
    glds16(src + (size_t)c * 32 * rstride, dst + c * 4096);
}

// ---------------- LayerNorm -> bf16 ----------------
__global__ __launch_bounds__(256) void ln_kernel(
    const float* __restrict__ x, const float* __restrict__ gamma,
    const float* __restrict__ beta, unsigned short* __restrict__ xn)
{
  int row = blockIdx.x;
  int t = threadIdx.x;
  const float* xr = x + (size_t)row * D_;
  float v0 = xr[t], v1 = xr[t + 256];
  float s = v0 + v1, ss = v0 * v0 + v1 * v1;
  #pragma unroll
  for (int m = 1; m < 64; m <<= 1) {
    s  += __shfl_xor(s, m);
    ss += __shfl_xor(ss, m);
  }
  __shared__ float red[8];
  int wid = t >> 6;
  if ((t & 63) == 0) { red[wid] = s; red[wid + 4] = ss; }
  __syncthreads();
  s  = red[0] + red[1] + red[2] + red[3];
  ss = red[4] + red[5] + red[6] + red[7];
  float mu  = s * (1.0f / D_);
  float var = ss * (1.0f / D_) - mu * mu;
  float rstd = rsqrtf(var + 1e-5f);
  unsigned short* o = xn + (size_t)row * D_;
  o[t]       = f2bf((v0 - mu) * rstd * gamma[t]       + beta[t]);
  o[t + 256] = f2bf((v1 - mu) * rstd * gamma[t + 256] + beta[t + 256]);
}

// ---------------- weight casts ----------------
__global__ __launch_bounds__(256) void cast_w_kernel(
    const float* __restrict__ wq, const float* __restrict__ wk,
    const float* __restrict__ wv, const float* __restrict__ wo,
    unsigned short* __restrict__ wqkv, unsigned short* __restrict__ wob)
{
  int i = blockIdx.x * 256 + threadIdx.x;   // 262144 total
  wqkv[i]          = f2bf(wq[i]);
  wqkv[i + 262144] = f2bf(wk[i]);
  wqkv[i + 524288] = f2bf(wv[i]);
  wob[i]           = f2bf(wo[i]);
}

// ---------------- QKV GEMM: q row-major, K/V in MFMA-fragment-packed layout -
// Kp chunk(bh,nt,j,ks) 1KB: lane l holds K[nt*64+j*16+(l&15)][ks*32+(l>>4)*8+0..7]
// Vp chunk(bh,nt,jd,jp) 1KB: lane l 16B = {Vt[jd*16+(l&15)][jp*32+(l>>4)*4+0..3],
//                                          same +16}
__global__ __launch_bounds__(256) void qkv_gemm(
    const unsigned short* __restrict__ xn,
    const unsigned short* __restrict__ wqkv,
    const float* __restrict__ bq, const float* __restrict__ bk,
    const float* __restrict__ bv,
    unsigned short* __restrict__ q, unsigned short* __restrict__ Kp,
    unsigned short* __restrict__ Vp)
{
  __shared__ __align__(16) char As[128 * 128];
  __shared__ __align__(16) char Bs[128 * 128];
  const int m0 = blockIdx.x * 128;
  const int n0 = blockIdx.y * 128;
  const int t = threadIdx.x, wid = t >> 6, lane = t & 63;
  const int wr = (wid >> 1) * 64, wc = (wid & 1) * 64;
  const int cl = lane & 15, rg = lane >> 4;
  const f32x4 z4 = {0.f, 0.f, 0.f, 0.f};
  const bool isv = (n0 >= 1024);

  const char* agb = (const char*)xn   + (size_t)m0 * 1024;
  const char* bgb = (const char*)wqkv + (size_t)n0 * 1024;

  f32x4 acc[4][4];
  #pragma unroll
  for (int i = 0; i < 4; ++i)
    #pragma unroll
    for (int j = 0; j < 4; ++j) acc[i][j] = z4;

  for (int k0 = 0; k0 < 512; k0 += 64) {
    __syncthreads();
    stage_tile(agb + k0 * 2, 1024, As, t);
    stage_tile(bgb + k0 * 2, 1024, Bs, t);
    __syncthreads();
    #pragma unroll
    for (int ks = 0; ks < 2; ++ks) {
      int koff = ks * 64 + rg * 16;
      bf16x8 af[4], bfr[4];
      #pragma unroll
      for (int i = 0; i < 4; ++i)
        af[i] = *(const bf16x8*)(As + swz128(wr + i * 16 + cl, koff));
      #pragma unroll
      for (int j = 0; j < 4; ++j)
        bfr[j] = *(const bf16x8*)(Bs + swz128(wc + j * 16 + cl, koff));
      if (isv) {
        #pragma unroll
        for (int i = 0; i < 4; ++i)
          #pragma unroll
          for (int j = 0; j < 4; ++j)
            acc[i][j] = __builtin_amdgcn_mfma_f32_16x16x32_bf16(af[i], bfr[j], acc[i][j], 0, 0, 0);
      } else {
        #pragma unroll
        for (int j = 0; j < 4; ++j)
          #pragma unroll
          for (int i = 0; i < 4; ++i)
            acc[j][i] = __builtin_amdgcn_mfma_f32_16x16x32_bf16(bfr[j], af[i], acc[j][i], 0, 0, 0);
      }
    }
  }

  if (isv) {
    // acc[i][j]: element (seq = mrow+r, d = n-col). 4 consecutive seq per store.
    #pragma unroll
    for (int j = 0; j < 4; ++j) {
      int n = n0 + wc + j * 16 + cl;
      int nn = n & 511;
      int h = nn >> 6, dh = nn & 63;
      int jd = dh >> 4, cld = dh & 15;
      float bias = bv[nn];
      #pragma unroll
      for (int i = 0; i < 4; ++i) {
        int mrow = m0 + wr + i * 16 + rg * 4;
        int b = mrow >> 11, mm = mrow & 2047;
        int nt = mm >> 6, nl = mm & 63;
        int jp = nl >> 5, half = (nl >> 4) & 1, rgv = (nl >> 2) & 3;
        u32x2 u;
        u[0] = cvtpk(acc[i][j][0] + bias, acc[i][j][1] + bias);
        u[1] = cvtpk(acc[i][j][2] + bias, acc[i][j][3] + bias);
        size_t off = ((((size_t)(b * H_ + h) * 32 + nt) * 4 + jd) * 2 + jp) * 512
                   + (rgv * 16 + cld) * 8 + half * 4;
        *(u16x4*)(Vp + off) = __builtin_bit_cast(u16x4, u);
      }
    }
  } else {
    const int mat = n0 >> 9;                  // 0: q, 1: k
    #pragma unroll
    for (int j = 0; j < 4; ++j) {
      int nn0 = ((n0 + wc) & 511) + j * 16 + rg * 4;
      int h = nn0 >> 6, dh = nn0 & 63;
      f32x4 b4 = *(const f32x4*)((mat ? bk : bq) + nn0);
      #pragma unroll
      for (int i = 0; i < 4; ++i) {
        int mrow = m0 + wr + i * 16 + cl;
        int b = mrow >> 11, mm = mrow & 2047;
        u32x2 u;
        u[0] = cvtpk(acc[j][i][0] + b4[0], acc[j][i][1] + b4[1]);
        u[1] = cvtpk(acc[j][i][2] + b4[2], acc[j][i][3] + b4[3]);
        if (mat == 0) {
          *(u16x4*)(q + ((size_t)(b * H_ + h) * M_ + mm) * DH_ + dh) =
              __builtin_bit_cast(u16x4, u);
        } else {
          int ks = dh >> 5, rgk = (dh >> 3) & 3, e0 = dh & 7;   // e0 in {0,4}
          size_t off = ((((size_t)(b * H_ + h) * 32 + (mm >> 6)) * 4 + ((mm >> 4) & 3)) * 2 + ks) * 512
                     + (rgk * 16 + (mm & 15)) * 8 + e0;
          *(u16x4*)(Kp + off) = __builtin_bit_cast(u16x4, u);
        }
      }
    }
  }
}

// ---------------- Attention v9: 32-row blocks, 8 blocks/CU, phase-mixed -----
// grid 2048 (XCD-swizzled); 32 rows/block, 2 waves x 16 rows. LDS 4KB (Ps).
__global__ __launch_bounds__(128, 4) void attn_kernel(
    const unsigned short* __restrict__ q,
    const unsigned short* __restrict__ Kp,
    const unsigned short* __restrict__ Vp,
    float* __restrict__ attn,
    unsigned short* __restrict__ ctx)
{
  __shared__ __align__(16) char Ps[2][2048];

  const int flat = blockIdx.x;
  const int bh = (flat & 7) * 4 + ((flat >> 3) >> 6);
  const int mb = (flat >> 3) & 63;                 // 64 m-blocks of 32 rows
  const int m0 = mb * 32;
  const int diag_nt = mb >> 1;                     // 64-col tile holding the diagonal
  const int t = threadIdx.x, wid = t >> 6, lane = t & 63;
  const int wr = wid * 16, cl = lane & 15, rg = lane >> 4;
  const int m_g = m0 + wr + cl;
  const f32x4 z4 = {0.f, 0.f, 0.f, 0.f};

  const char* qb = (const char*)(q + (size_t)bh * M_ * DH_);
  const unsigned short* kpb = Kp + (size_t)bh * 131072;   // 256 KB per bh
  const unsigned short* vpb = Vp + (size_t)bh * 131072;
  float* ab = attn + (size_t)bh * M_ * M_;

  bf16x8 qf[2];
  #pragma unroll
  for (int ks = 0; ks < 2; ++ks)
    qf[ks] = *(const bf16x8*)(qb + (size_t)m_g * 128 + ks * 64 + rg * 16);

  // ---- pass 1: psum (no barriers, K fragments straight from packed L2) ----
  float psum = 0.f;
  for (int nt = 0; nt < 32; ++nt) {
    const unsigned short* kch = kpb + (size_t)nt * 4096;
    f32x4 s[4];
    #pragma unroll
    for (int j = 0; j < 4; ++j) s[j] = z4;
    #pragma unroll
    for (int ks = 0; ks < 2; ++ks)
      #pragma unroll
      for (int j = 0; j < 4; ++j) {
        bf16x8 kf = *(const bf16x8*)(kch + (j * 2 + ks) * 512 + lane * 8);
        s[j] = __builtin_amdgcn_mfma_f32_16x16x32_bf16(kf, qf[ks], s[j], 0, 0, 0);
      }
    if (nt == diag_nt) {
      #pragma unroll
      for (int j = 0; j < 4; ++j)
        #pragma unroll
        for (int r = 0; r < 4; ++r) {
          int n_g = nt * 64 + j * 16 + rg * 4 + r;
          float p = __builtin_amdgcn_exp2f(s[j][r] * EXPC);
          psum += (n_g == m_g) ? 0.f : p;
        }
    } else {
      #pragma unroll
      for (int j = 0; j < 4; ++j)
        #pragma unroll
        for (int r = 0; r < 4; ++r)
          psum += __builtin_amdgcn_exp2f(s[j][r] * EXPC);
    }
  }
  psum += __shfl_xor(psum, 16);
  psum += __shfl_xor(psum, 32);
  const float rv = 1.0f / psum;

  // ---- pass 2: recompute S, attn store, PV via direct register feed ----
  f32x4 oc[4];
  #pragma unroll
  for (int j = 0; j < 4; ++j) oc[j] = z4;

  const int srow = lane >> 4;          // attn-store row-in-group 0..3
  const int sch  = lane & 15;          // attn-store 16B-chunk 0..15

  asm volatile("s_nop 7" :::);         // VALU init -> asm MFMA srcC guard

  for (int nt = 0; nt < 32; ++nt) {
    const unsigned short* kch = kpb + (size_t)nt * 4096;
    const unsigned short* vch = vpb + (size_t)nt * 4096;
    f32x4 s[4];
    #pragma unroll
    for (int j = 0; j < 4; ++j) s[j] = z4;
    #pragma unroll
    for (int ks = 0; ks < 2; ++ks)
      #pragma unroll
      for (int j = 0; j < 4; ++j) {
        bf16x8 kf = *(const bf16x8*)(kch + (j * 2 + ks) * 512 + lane * 8);
        s[j] = __builtin_amdgcn_mfma_f32_16x16x32_bf16(kf, qf[ks], s[j], 0, 0, 0);
      }
    // P: normalized, diag-masked; bf16x4 per j feeds PV directly (B-operand
    // of 16x16x16: col=lane&15=m, k=(lane>>4)*4+0..3=n -- exact S layout).
    const bool dtile = (nt == diag_nt);
    bf16x4 pb[4];
    #pragma unroll
    for (int j = 0; j < 4; ++j) {
      f32x4 pv;
      #pragma unroll
      for (int r = 0; r < 4; ++r) {
        int n_g = nt * 64 + j * 16 + rg * 4 + r;
        float p = __builtin_amdgcn_exp2f(s[j][r] * EXPC) * rv;
        pv[r] = (dtile && n_g == m_g) ? 0.f : p;
      }
      u32x2 u;
      u[0] = cvtpk(pv[0], pv[1]);
      u[1] = cvtpk(pv[2], pv[3]);
      pb[j] = __builtin_bit_cast(bf16x4, u);
      *(u32x2*)(Ps[wid] + swz128(cl, j * 32 + rg * 8)) = u;  // per-wave: no barrier
    }
    // attn store: dense 4 rows x 256B per instruction group (NT, stays in flight)
    {
      float* abase = ab + ((size_t)(m0 + wr + srow)) * M_ + nt * 64 + sch * 4;
      #pragma unroll
      for (int it = 0; it < 4; ++it) {
        u16x4 pu = *(const u16x4*)(Ps[wid] + swz128(it * 4 + srow, sch * 8));
        f32x4 pv;
        #pragma unroll
        for (int r = 0; r < 4; ++r) pv[r] = __uint_as_float((unsigned)pu[r] << 16);
        __builtin_nontemporal_store(pv, (f32x4*)(abase + (size_t)it * 4 * M_));
      }
    }
    // PV: oc[jd](d rows, m cols) += Vt-frag x P-frag, K=16 per j
    #pragma unroll
    for (int jp = 0; jp < 2; ++jp)
      #pragma unroll
      for (int jd = 0; jd < 4; ++jd) {
        bf16x8 w = *(const bf16x8*)(vch + (jd * 2 + jp) * 512 + lane * 8);
        bf16x4 vlo = __builtin_shufflevector(w, w, 0, 1, 2, 3);
        bf16x4 vhi = __builtin_shufflevector(w, w, 4, 5, 6, 7);
        oc[jd] = mfma16(vlo, pb[jp * 2],     oc[jd]);
        oc[jd] = mfma16(vhi, pb[jp * 2 + 1], oc[jd]);
      }
  }

  asm volatile("s_nop 7\n\ts_nop 7" :::);   // asm MFMA -> VALU read guard

  // ctx epilogue: lane holds 4 consecutive d for its row m_g
  int b = bh >> 3, h = bh & 7;
  unsigned short* crow = ctx + ((size_t)b * M_ + m_g) * D_ + h * DH_ + rg * 4;
  #pragma unroll
  for (int jd = 0; jd < 4; ++jd) {
    u32x2 u;
    u[0] = cvtpk(oc[jd][0], oc[jd][1]);
    u[1] = cvtpk(oc[jd][2], oc[jd][3]);
    *(u32x2*)(crow + jd * 16) = u;
  }
}

// ---------------- out = ctx @ wo^T + bo + x (glds staging) ------------------
__global__ __launch_bounds__(256) void out_gemm(
    const unsigned short* __restrict__ ctxb,
    const unsigned short* __restrict__ wob,
    const float* __restrict__ bo,
    const float* __restrict__ x,
    float* __restrict__ out)
{
  __shared__ __align__(16) char As[128 * 128];
  __shared__ __align__(16) char Bs[128 * 128];
  const int m0 = blockIdx.x * 128;
  const int n0 = blockIdx.y * 128;
  const int t = threadIdx.x, wid = t >> 6, lane = t & 63;
  const int wr = (wid >> 1) * 64, wc = (wid & 1) * 64;
  const int cl = lane & 15, rg = lane >> 4;
  const f32x4 z4 = {0.f, 0.f, 0.f, 0.f};

  const char* agb = (const char*)ctxb + (size_t)m0 * 1024;
  const char* bgb = (const char*)wob  + (size_t)n0 * 1024;

  f32x4 acc[4][4];   // [j: n frag][i: m frag], row=n, col=m
  #pragma unroll
  for (int j = 0; j < 4; ++j)
    #pragma unroll
    for (int i = 0; i < 4; ++i) acc[j][i] = z4;

  for (int k0 = 0; k0 < 512; k0 += 64) {
    __syncthreads();
    stage_tile(agb + k0 * 2, 1024, As, t);
    stage_tile(bgb + k0 * 2, 1024, Bs, t);
    __syncthreads();
    #pragma unroll
    for (int ks = 0; ks < 2; ++ks) {
      int koff = ks * 64 + rg * 16;
      bf16x8 af[4], bfr[4];
      #pragma unroll
      for (int i = 0; i < 4; ++i)
        af[i] = *(const bf16x8*)(As + swz128(wr + i * 16 + cl, koff));
      #pragma unroll
      for (int j = 0; j < 4; ++j)
        bfr[j] = *(const bf16x8*)(Bs + swz128(wc + j * 16 + cl, koff));
      #pragma unroll
      for (int j = 0; j < 4; ++j)
        #pragma unroll
        for (int i = 0; i < 4; ++i)
          acc[j][i] = __builtin_amdgcn_mfma_f32_16x16x32_bf16(bfr[j], af[i], acc[j][i], 0, 0, 0);
    }
  }

  #pragma unroll
  for (int j = 0; j < 4; ++j) {
    int nb = n0 + wc + j * 16 + rg * 4;
    f32x4 bo4 = *(const f32x4*)(bo + nb);
    #pragma unroll
    for (int i = 0; i < 4; ++i) {
      int m = m0 + wr + i * 16 + cl;
      f32x4 x4 = *(const f32x4*)(x + (size_t)m * 512 + nb);
      f32x4 o;
      #pragma unroll
      for (int r = 0; r < 4; ++r) o[r] = acc[j][i][r] + bo4[r] + x4[r];
      *(f32x4*)(out + (size_t)m * 512 + nb) = o;
    }
  }
}

extern "C" void kernel_launch(void* const* d_in, const int* in_sizes, int n_in,
                              void* d_out, int out_size, void* d_ws, size_t ws_size,
                              hipStream_t stream) {
  const float* x     = (const float*)d_in[0];
  const float* wq    = (const float*)d_in[1];
  const float* bq    = (const float*)d_in[2];
  const float* wk    = (const float*)d_in[3];
  const float* bk    = (const float*)d_in[4];
  const float* wv    = (const float*)d_in[5];
  const float* bv    = (const float*)d_in[6];
  const float* wo    = (const float*)d_in[7];
  const float* bo    = (const float*)d_in[8];
  const float* gamma = (const float*)d_in[9];
  const float* beta  = (const float*)d_in[10];

  char* ws = (char*)d_ws;
  unsigned short* xn   = (unsigned short*)(ws);              //  8,388,608 B
  unsigned short* wqkv = (unsigned short*)(ws + 8388608);    //  1,572,864 B
  unsigned short* wob  = (unsigned short*)(ws + 9961472);    //    524,288 B
  unsigned short* qb   = (unsigned short*)(ws + 10485760);   //  8,388,608 B
  unsigned short* Kp   = (unsigned short*)(ws + 18874368);   //  8,388,608 B (packed)
  unsigned short* Vp   = (unsigned short*)(ws + 27262976);   //  8,388,608 B (packed)
  unsigned short* ctx  = (unsigned short*)(ws + 35651584);   //  8,388,608 B

  float* out  = (float*)d_out;
  float* attn = (float*)d_out + 4194304;

  ln_kernel<<<8192, 256, 0, stream>>>(x, gamma, beta, xn);
  cast_w_kernel<<<1024, 256, 0, stream>>>(wq, wk, wv, wo, wqkv, wob);
  qkv_gemm<<<dim3(64, 12), 256, 0, stream>>>(xn, wqkv, bq, bk, bv, qb, Kp, Vp);
  attn_kernel<<<2048, 128, 0, stream>>>(qb, Kp, Vp, attn, ctx);
  out_gemm<<<dim3(64, 4), 256, 0, stream>>>(ctx, wob, bo, x, out);
}

// Round 10
// 199.012 us; speedup vs baseline: 1.0521x; 1.0521x over previous
//
#include <hip/hip_runtime.h>

#define B_   4
#define H_   8
#define M_   2048
#define D_   512
#define DH_  64

typedef short  bf16x8 __attribute__((ext_vector_type(8)));
typedef short  bf16x4 __attribute__((ext_vector_type(4)));
typedef float  f32x4  __attribute__((ext_vector_type(4)));
typedef unsigned short u16x4 __attribute__((ext_vector_type(4)));
typedef unsigned int   u32x2 __attribute__((ext_vector_type(2)));

#define EXPC 0.18033688011112042f   /* log2(e)/8 : exp(s/8) == exp2(s*EXPC) */

static __device__ __forceinline__ unsigned short f2bf(float f) {
  unsigned u = __float_as_uint(f);
  u += 0x7fffu + ((u >> 16) & 1u);
  return (unsigned short)(u >> 16);
}

// one instruction: [bf16(lo), bf16(hi)] packed into a u32 (RNE)
static __device__ __forceinline__ unsigned cvtpk(float lo, float hi) {
  unsigned r;
  asm("v_cvt_pk_bf16_f32 %0, %1, %2" : "=v"(r) : "v"(lo), "v"(hi));
  return r;
}

// PV matrix op: D = A(4 bf16, d-rows) x B(4 bf16, n-k) + C. ISA cdna4 §10.
static __device__ __forceinline__ f32x4 mfma16(bf16x4 a, bf16x4 b, f32x4 c) {
  asm("v_mfma_f32_16x16x16_bf16 %0, %1, %2, %0" : "+v"(c) : "v"(a), "v"(b));
  return c;
}

static __device__ __forceinline__ int swz128(int row, int byteoff) {
  return row * 128 + (byteoff ^ ((row & 7) << 4));
}

// async global->LDS, 16B per lane, LDS dest = wave-uniform base + lane*16
static __device__ __forceinline__ void glds16(const void* g, void* l) {
  __builtin_amdgcn_global_load_lds(
      (const __attribute__((address_space(1))) unsigned*)g,
      (__attribute__((address_space(3))) unsigned*)l, 16, 0, 0);
}

// stage a 128-row x 128-byte tile (16KB) into LDS in swz128 layout
static __device__ __forceinline__ void stage_tile(
    const char* g0, size_t rstride, char* lds, int t) {
  const int r0 = t >> 3, c0 = t & 7;
  const char* src = g0 + (size_t)r0 * rstride + ((c0 ^ (r0 & 7)) << 4);
  char* dst = lds + ((t & 192) << 4);
  #pragma unroll
  for (int c = 0; c < 4; ++c)
    glds16(src + (size_t)c * 32 * rstride, dst + c * 4096);
}

// stage a 64-row x 128-byte tile (8KB) into LDS in swz128 layout
static __device__ __forceinline__ void stage64(
    const char* g0, size_t rstride, char* lds, int t) {
  #pragma unroll
  for (int c = 0; c < 2; ++c) {
    int s = c * 256 + t;
    int row = s >> 3, ch = s & 7;
    const char* src = g0 + (size_t)row * rstride + ((ch ^ (row & 7)) << 4);
    glds16(src, lds + c * 4096 + ((t & 192) << 4));
  }
}

// ---------------- LayerNorm -> bf16 ----------------
__global__ __launch_bounds__(256) void ln_kernel(
    const float* __restrict__ x, const float* __restrict__ gamma,
    const float* __restrict__ beta, unsigned short* __restrict__ xn)
{
  int row = blockIdx.x;
  int t = threadIdx.x;
  const float* xr = x + (size_t)row * D_;
  float v0 = xr[t], v1 = xr[t + 256];
  float s = v0 + v1, ss = v0 * v0 + v1 * v1;
  #pragma unroll
  for (int m = 1; m < 64; m <<= 1) {
    s  += __shfl_xor(s, m);
    ss += __shfl_xor(ss, m);
  }
  __shared__ float red[8];
  int wid = t >> 6;
  if ((t & 63) == 0) { red[wid] = s; red[wid + 4] = ss; }
  __syncthreads();
  s  = red[0] + red[1] + red[2] + red[3];
  ss = red[4] + red[5] + red[6] + red[7];
  float mu  = s * (1.0f / D_);
  float var = ss * (1.0f / D_) - mu * mu;
  float rstd = rsqrtf(var + 1e-5f);
  unsigned short* o = xn + (size_t)row * D_;
  o[t]       = f2bf((v0 - mu) * rstd * gamma[t]       + beta[t]);
  o[t + 256] = f2bf((v1 - mu) * rstd * gamma[t + 256] + beta[t + 256]);
}

// ---------------- weight casts ----------------
__global__ __launch_bounds__(256) void cast_w_kernel(
    const float* __restrict__ wq, const float* __restrict__ wk,
    const float* __restrict__ wv, const float* __restrict__ wo,
    unsigned short* __restrict__ wqkv, unsigned short* __restrict__ wob)
{
  int i = blockIdx.x * 256 + threadIdx.x;   // 262144 total
  wqkv[i]          = f2bf(wq[i]);
  wqkv[i + 262144] = f2bf(wk[i]);
  wqkv[i + 524288] = f2bf(wv[i]);
  wob[i]           = f2bf(wo[i]);
}

// ---------------- QKV GEMM: q row-major, K/V in MFMA-fragment-packed layout -
__global__ __launch_bounds__(256) void qkv_gemm(
    const unsigned short* __restrict__ xn,
    const unsigned short* __restrict__ wqkv,
    const float* __restrict__ bq, const float* __restrict__ bk,
    const float* __restrict__ bv,
    unsigned short* __restrict__ q, unsigned short* __restrict__ Kp,
    unsigned short* __restrict__ Vp)
{
  __shared__ __align__(16) char As[128 * 128];
  __shared__ __align__(16) char Bs[128 * 128];
  const int m0 = blockIdx.x * 128;
  const int n0 = blockIdx.y * 128;
  const int t = threadIdx.x, wid = t >> 6, lane = t & 63;
  const int wr = (wid >> 1) * 64, wc = (wid & 1) * 64;
  const int cl = lane & 15, rg = lane >> 4;
  const f32x4 z4 = {0.f, 0.f, 0.f, 0.f};
  const bool isv = (n0 >= 1024);

  const char* agb = (const char*)xn   + (size_t)m0 * 1024;
  const char* bgb = (const char*)wqkv + (size_t)n0 * 1024;

  f32x4 acc[4][4];
  #pragma unroll
  for (int i = 0; i < 4; ++i)
    #pragma unroll
    for (int j = 0; j < 4; ++j) acc[i][j] = z4;

  for (int k0 = 0; k0 < 512; k0 += 64) {
    __syncthreads();
    stage_tile(agb + k0 * 2, 1024, As, t);
    stage_tile(bgb + k0 * 2, 1024, Bs, t);
    __syncthreads();
    #pragma unroll
    for (int ks = 0; ks < 2; ++ks) {
      int koff = ks * 64 + rg * 16;
      bf16x8 af[4], bfr[4];
      #pragma unroll
      for (int i = 0; i < 4; ++i)
        af[i] = *(const bf16x8*)(As + swz128(wr + i * 16 + cl, koff));
      #pragma unroll
      for (int j = 0; j < 4; ++j)
        bfr[j] = *(const bf16x8*)(Bs + swz128(wc + j * 16 + cl, koff));
      if (isv) {
        #pragma unroll
        for (int i = 0; i < 4; ++i)
          #pragma unroll
          for (int j = 0; j < 4; ++j)
            acc[i][j] = __builtin_amdgcn_mfma_f32_16x16x32_bf16(af[i], bfr[j], acc[i][j], 0, 0, 0);
      } else {
        #pragma unroll
        for (int j = 0; j < 4; ++j)
          #pragma unroll
          for (int i = 0; i < 4; ++i)
            acc[j][i] = __builtin_amdgcn_mfma_f32_16x16x32_bf16(bfr[j], af[i], acc[j][i], 0, 0, 0);
      }
    }
  }

  if (isv) {
    #pragma unroll
    for (int j = 0; j < 4; ++j) {
      int n = n0 + wc + j * 16 + cl;
      int nn = n & 511;
      int h = nn >> 6, dh = nn & 63;
      int jd = dh >> 4, cld = dh & 15;
      float bias = bv[nn];
      #pragma unroll
      for (int i = 0; i < 4; ++i) {
        int mrow = m0 + wr + i * 16 + rg * 4;
        int b = mrow >> 11, mm = mrow & 2047;
        int nt = mm >> 6, nl = mm & 63;
        int jp = nl >> 5, half = (nl >> 4) & 1, rgv = (nl >> 2) & 3;
        u32x2 u;
        u[0] = cvtpk(acc[i][j][0] + bias, acc[i][j][1] + bias);
        u[1] = cvtpk(acc[i][j][2] + bias, acc[i][j][3] + bias);
        size_t off = ((((size_t)(b * H_ + h) * 32 + nt) * 4 + jd) * 2 + jp) * 512
                   + (rgv * 16 + cld) * 8 + half * 4;
        *(u16x4*)(Vp + off) = __builtin_bit_cast(u16x4, u);
      }
    }
  } else {
    const int mat = n0 >> 9;                  // 0: q, 1: k
    #pragma unroll
    for (int j = 0; j < 4; ++j) {
      int nn0 = ((n0 + wc) & 511) + j * 16 + rg * 4;
      int h = nn0 >> 6, dh = nn0 & 63;
      f32x4 b4 = *(const f32x4*)((mat ? bk : bq) + nn0);
      #pragma unroll
      for (int i = 0; i < 4; ++i) {
        int mrow = m0 + wr + i * 16 + cl;
        int b = mrow >> 11, mm = mrow & 2047;
        u32x2 u;
        u[0] = cvtpk(acc[j][i][0] + b4[0], acc[j][i][1] + b4[1]);
        u[1] = cvtpk(acc[j][i][2] + b4[2], acc[j][i][3] + b4[3]);
        if (mat == 0) {
          *(u16x4*)(q + ((size_t)(b * H_ + h) * M_ + mm) * DH_ + dh) =
              __builtin_bit_cast(u16x4, u);
        } else {
          int ks = dh >> 5, rgk = (dh >> 3) & 3, e0 = dh & 7;   // e0 in {0,4}
          size_t off = ((((size_t)(b * H_ + h) * 32 + (mm >> 6)) * 4 + ((mm >> 4) & 3)) * 2 + ks) * 512
                     + (rgk * 16 + (mm & 15)) * 8 + e0;
          *(u16x4*)(Kp + off) = __builtin_bit_cast(u16x4, u);
        }
      }
    }
  }
}

// ---------------- Attention v10: staggered A/B units, overlap p1/p2 ---------
// grid 512 (XCD-swizzled); block = 256 thr (4 waves), covers 128 rows:
//   A = [m0, m0+64), B = [m0+64, m0+128), each wave owns 16 rows of each.
__global__ __launch_bounds__(256, 2) void attn_kernel(
    const unsigned short* __restrict__ q,
    const unsigned short* __restrict__ Kp,
    const unsigned short* __restrict__ Vp,
    float* __restrict__ attn,
    unsigned short* __restrict__ ctx)
{
  __shared__ __align__(16) char Ps[4][2048];

  const int flat = blockIdx.x;
  const int bh = (flat & 7) * 4 + ((flat >> 3) >> 4);
  const int u  = (flat >> 3) & 15;                 // 16 units of 128 rows
  const int m0 = u * 128;
  const int ntA = u * 2, ntB = u * 2 + 1;          // diag tiles of A and B
  const int t = threadIdx.x, wid = t >> 6, lane = t & 63;
  const int wr = wid * 16, cl = lane & 15, rg = lane >> 4;
  const int mA = m0 + wr + cl;
  const int mB = mA + 64;
  const f32x4 z4 = {0.f, 0.f, 0.f, 0.f};

  const char* qb = (const char*)(q + (size_t)bh * M_ * DH_);
  const unsigned short* kpb = Kp + (size_t)bh * 131072;   // 256 KB per bh
  const unsigned short* vpb = Vp + (size_t)bh * 131072;
  float* ab = attn + (size_t)bh * M_ * M_;

  bf16x8 qfA[2], qfB[2];
  #pragma unroll
  for (int ks = 0; ks < 2; ++ks) {
    qfA[ks] = *(const bf16x8*)(qb + (size_t)mA * 128 + ks * 64 + rg * 16);
    qfB[ks] = *(const bf16x8*)(qb + (size_t)mB * 128 + ks * 64 + rg * 16);
  }

  const int srow = lane >> 4;          // attn-store row-in-group 0..3
  const int sch  = lane & 15;          // attn-store 16B-chunk 0..15

  // ================= phase 1: psum(A) =================
  float psumA = 0.f;
  for (int nt = 0; nt < 32; ++nt) {
    const unsigned short* kch = kpb + (size_t)nt * 4096;
    f32x4 s[4];
    #pragma unroll
    for (int j = 0; j < 4; ++j) s[j] = z4;
    #pragma unroll
    for (int ks = 0; ks < 2; ++ks)
      #pragma unroll
      for (int j = 0; j < 4; ++j) {
        bf16x8 kf = *(const bf16x8*)(kch + (j * 2 + ks) * 512 + lane * 8);
        s[j] = __builtin_amdgcn_mfma_f32_16x16x32_bf16(kf, qfA[ks], s[j], 0, 0, 0);
      }
    if (nt == ntA) {
      #pragma unroll
      for (int j = 0; j < 4; ++j)
        #pragma unroll
        for (int r = 0; r < 4; ++r) {
          int n_g = nt * 64 + j * 16 + rg * 4 + r;
          float p = __builtin_amdgcn_exp2f(s[j][r] * EXPC);
          psumA += (n_g == mA) ? 0.f : p;
        }
    } else {
      #pragma unroll
      for (int j = 0; j < 4; ++j)
        #pragma unroll
        for (int r = 0; r < 4; ++r)
          psumA += __builtin_amdgcn_exp2f(s[j][r] * EXPC);
    }
  }
  psumA += __shfl_xor(psumA, 16);
  psumA += __shfl_xor(psumA, 32);
  const float rvA = 1.0f / psumA;

  asm volatile("s_nop 7" :::);         // VALU init -> asm MFMA srcC guard

  // ============ phase 2: pass2(A) interleaved with psum(B) ============
  f32x4 ocA[4];
  #pragma unroll
  for (int j = 0; j < 4; ++j) ocA[j] = z4;
  float psumB = 0.f;

  for (int nt = 0; nt < 32; ++nt) {
    const unsigned short* kch = kpb + (size_t)nt * 4096;
    const unsigned short* vch = vpb + (size_t)nt * 4096;
    bf16x8 kf[8], vf[8];
    #pragma unroll
    for (int jk = 0; jk < 8; ++jk)
      kf[jk] = *(const bf16x8*)(kch + jk * 512 + lane * 8);
    #pragma unroll
    for (int jk = 0; jk < 8; ++jk)
      vf[jk] = *(const bf16x8*)(vch + jk * 512 + lane * 8);
    // QK(A)
    f32x4 s[4];
    #pragma unroll
    for (int j = 0; j < 4; ++j) s[j] = z4;
    #pragma unroll
    for (int ks = 0; ks < 2; ++ks)
      #pragma unroll
      for (int j = 0; j < 4; ++j)
        s[j] = __builtin_amdgcn_mfma_f32_16x16x32_bf16(kf[j * 2 + ks], qfA[ks], s[j], 0, 0, 0);
    // P(A) -> pb + Ps
    const bool dA = (nt == ntA);
    bf16x4 pb[4];
    #pragma unroll
    for (int j = 0; j < 4; ++j) {
      f32x4 pv;
      #pragma unroll
      for (int r = 0; r < 4; ++r) {
        int n_g = nt * 64 + j * 16 + rg * 4 + r;
        float p = __builtin_amdgcn_exp2f(s[j][r] * EXPC) * rvA;
        pv[r] = (dA && n_g == mA) ? 0.f : p;
      }
      u32x2 uu;
      uu[0] = cvtpk(pv[0], pv[1]);
      uu[1] = cvtpk(pv[2], pv[3]);
      pb[j] = __builtin_bit_cast(bf16x4, uu);
      *(u32x2*)(Ps[wid] + swz128(cl, j * 32 + rg * 8)) = uu;
    }
    // attn stores (A): NT, stay in flight
    {
      float* abase = ab + ((size_t)(m0 + wr + srow)) * M_ + nt * 64 + sch * 4;
      #pragma unroll
      for (int it = 0; it < 4; ++it) {
        u16x4 pu = *(const u16x4*)(Ps[wid] + swz128(it * 4 + srow, sch * 8));
        f32x4 pv;
        #pragma unroll
        for (int r = 0; r < 4; ++r) pv[r] = __uint_as_float((unsigned)pu[r] << 16);
        __builtin_nontemporal_store(pv, (f32x4*)(abase + (size_t)it * 4 * M_));
      }
    }
    // PV(A)
    #pragma unroll
    for (int jp = 0; jp < 2; ++jp)
      #pragma unroll
      for (int jd = 0; jd < 4; ++jd) {
        bf16x8 w = vf[jd * 2 + jp];
        bf16x4 vlo = __builtin_shufflevector(w, w, 0, 1, 2, 3);
        bf16x4 vhi = __builtin_shufflevector(w, w, 4, 5, 6, 7);
        ocA[jd] = mfma16(vlo, pb[jp * 2],     ocA[jd]);
        ocA[jd] = mfma16(vhi, pb[jp * 2 + 1], ocA[jd]);
      }
    // QK(B) on the SAME kf + psum(B)  (compute overlaps A's store stream)
    #pragma unroll
    for (int j = 0; j < 4; ++j) s[j] = z4;
    #pragma unroll
    for (int ks = 0; ks < 2; ++ks)
      #pragma unroll
      for (int j = 0; j < 4; ++j)
        s[j] = __builtin_amdgcn_mfma_f32_16x16x32_bf16(kf[j * 2 + ks], qfB[ks], s[j], 0, 0, 0);
    if (nt == ntB) {
      #pragma unroll
      for (int j = 0; j < 4; ++j)
        #pragma unroll
        for (int r = 0; r < 4; ++r) {
          int n_g = nt * 64 + j * 16 + rg * 4 + r;
          float p = __builtin_amdgcn_exp2f(s[j][r] * EXPC);
          psumB += (n_g == mB) ? 0.f : p;
        }
    } else {
      #pragma unroll
      for (int j = 0; j < 4; ++j)
        #pragma unroll
        for (int r = 0; r < 4; ++r)
          psumB += __builtin_amdgcn_exp2f(s[j][r] * EXPC);
    }
  }
  psumB += __shfl_xor(psumB, 16);
  psumB += __shfl_xor(psumB, 32);
  const float rvB = 1.0f / psumB;

  // ctx epilogue A
  {
    int b = bh >> 3, h = bh & 7;
    asm volatile("s_nop 7\n\ts_nop 7" :::);
    unsigned short* crow = ctx + ((size_t)b * M_ + mA) * D_ + h * DH_ + rg * 4;
    #pragma unroll
    for (int jd = 0; jd < 4; ++jd) {
      u32x2 uu;
      uu[0] = cvtpk(ocA[jd][0], ocA[jd][1]);
      uu[1] = cvtpk(ocA[jd][2], ocA[jd][3]);
      *(u32x2*)(crow + jd * 16) = uu;
    }
  }

  // ================= phase 3: pass2(B) =================
  f32x4 ocB[4];
  #pragma unroll
  for (int j = 0; j < 4; ++j) ocB[j] = z4;
  asm volatile("s_nop 7" :::);

  for (int nt = 0; nt < 32; ++nt) {
    const unsigned short* kch = kpb + (size_t)nt * 4096;
    const unsigned short* vch = vpb + (size_t)nt * 4096;
    f32x4 s[4];
    #pragma unroll
    for (int j = 0; j < 4; ++j) s[j] = z4;
    #pragma unroll
    for (int ks = 0; ks < 2; ++ks)
      #pragma unroll
      for (int j = 0; j < 4; ++j) {
        bf16x8 kf = *(const bf16x8*)(kch + (j * 2 + ks) * 512 + lane * 8);
        s[j] = __builtin_amdgcn_mfma_f32_16x16x32_bf16(kf, qfB[ks], s[j], 0, 0, 0);
      }
    const bool dB = (nt == ntB);
    bf16x4 pb[4];
    #pragma unroll
    for (int j = 0; j < 4; ++j) {
      f32x4 pv;
      #pragma unroll
      for (int r = 0; r < 4; ++r) {
        int n_g = nt * 64 + j * 16 + rg * 4 + r;
        float p = __builtin_amdgcn_exp2f(s[j][r] * EXPC) * rvB;
        pv[r] = (dB && n_g == mB) ? 0.f : p;
      }
      u32x2 uu;
      uu[0] = cvtpk(pv[0], pv[1]);
      uu[1] = cvtpk(pv[2], pv[3]);
      pb[j] = __builtin_bit_cast(bf16x4, uu);
      *(u32x2*)(Ps[wid] + swz128(cl, j * 32 + rg * 8)) = uu;
    }
    {
      float* abase = ab + ((size_t)(m0 + 64 + wr + srow)) * M_ + nt * 64 + sch * 4;
      #pragma unroll
      for (int it = 0; it < 4; ++it) {
        u16x4 pu = *(const u16x4*)(Ps[wid] + swz128(it * 4 + srow, sch * 8));
        f32x4 pv;
        #pragma unroll
        for (int r = 0; r < 4; ++r) pv[r] = __uint_as_float((unsigned)pu[r] << 16);
        __builtin_nontemporal_store(pv, (f32x4*)(abase + (size_t)it * 4 * M_));
      }
    }
    #pragma unroll
    for (int jp = 0; jp < 2; ++jp)
      #pragma unroll
      for (int jd = 0; jd < 4; ++jd) {
        bf16x8 w = *(const bf16x8*)(vch + (jd * 2 + jp) * 512 + lane * 8);
        bf16x4 vlo = __builtin_shufflevector(w, w, 0, 1, 2, 3);
        bf16x4 vhi = __builtin_shufflevector(w, w, 4, 5, 6, 7);
        ocB[jd] = mfma16(vlo, pb[jp * 2],     ocB[jd]);
        ocB[jd] = mfma16(vhi, pb[jp * 2 + 1], ocB[jd]);
      }
  }

  asm volatile("s_nop 7\n\ts_nop 7" :::);   // asm MFMA -> VALU read guard

  // ctx epilogue B
  {
    int b = bh >> 3, h = bh & 7;
    unsigned short* crow = ctx + ((size_t)b * M_ + mB) * D_ + h * DH_ + rg * 4;
    #pragma unroll
    for (int jd = 0; jd < 4; ++jd) {
      u32x2 uu;
      uu[0] = cvtpk(ocB[jd][0], ocB[jd][1]);
      uu[1] = cvtpk(ocB[jd][2], ocB[jd][3]);
      *(u32x2*)(crow + jd * 16) = uu;
    }
  }
}

// ---------------- out = ctx @ wo^T + bo + x (128x64 tiles, 2 blocks/CU) -----
__global__ __launch_bounds__(256) void out_gemm(
    const unsigned short* __restrict__ ctxb,
    const unsigned short* __restrict__ wob,
    const float* __restrict__ bo,
    const float* __restrict__ x,
    float* __restrict__ out)
{
  __shared__ __align__(16) char As[128 * 128];
  __shared__ __align__(16) char Bs[64 * 128];
  const int m0 = blockIdx.x * 128;
  const int n0 = blockIdx.y * 64;
  const int t = threadIdx.x, wid = t >> 6, lane = t & 63;
  const int wr = (wid >> 1) * 64, wc = (wid & 1) * 32;
  const int cl = lane & 15, rg = lane >> 4;
  const f32x4 z4 = {0.f, 0.f, 0.f, 0.f};

  const char* agb = (const char*)ctxb + (size_t)m0 * 1024;
  const char* bgb = (const char*)wob  + (size_t)n0 * 1024;

  f32x4 acc[2][4];   // [j: n frag][i: m frag], row=n, col=m
  #pragma unroll
  for (int j = 0; j < 2; ++j)
    #pragma unroll
    for (int i = 0; i < 4; ++i) acc[j][i] = z4;

  for (int k0 = 0; k0 < 512; k0 += 64) {
    __syncthreads();
    stage_tile(agb + k0 * 2, 1024, As, t);
    stage64(bgb + k0 * 2, 1024, Bs, t);
    __syncthreads();
    #pragma unroll
    for (int ks = 0; ks < 2; ++ks) {
      int koff = ks * 64 + rg * 16;
      bf16x8 af[4], bfr[2];
      #pragma unroll
      for (int i = 0; i < 4; ++i)
        af[i] = *(const bf16x8*)(As + swz128(wr + i * 16 + cl, koff));
      #pragma unroll
      for (int j = 0; j < 2; ++j)
        bfr[j] = *(const bf16x8*)(Bs + swz128(wc + j * 16 + cl, koff));
      #pragma unroll
      for (int j = 0; j < 2; ++j)
        #pragma unroll
        for (int i = 0; i < 4; ++i)
          acc[j][i] = __builtin_amdgcn_mfma_f32_16x16x32_bf16(bfr[j], af[i], acc[j][i], 0, 0, 0);
    }
  }

  #pragma unroll
  for (int j = 0; j < 2; ++j) {
    int nb = n0 + wc + j * 16 + rg * 4;
    f32x4 bo4 = *(const f32x4*)(bo + nb);
    #pragma unroll
    for (int i = 0; i < 4; ++i) {
      int m = m0 + wr + i * 16 + cl;
      f32x4 x4 = *(const f32x4*)(x + (size_t)m * 512 + nb);
      f32x4 o;
      #pragma unroll
      for (int r = 0; r < 4; ++r) o[r] = acc[j][i][r] + bo4[r] + x4[r];
      *(f32x4*)(out + (size_t)m * 512 + nb) = o;
    }
  }
}

extern "C" void kernel_launch(void* const* d_in, const int* in_sizes, int n_in,
                              void* d_out, int out_size, void* d_ws, size_t ws_size,
                              hipStream_t stream) {
  const float* x     = (const float*)d_in[0];
  const float* wq    = (const float*)d_in[1];
  const float* bq    = (const float*)d_in[2];
  const float* wk    = (const float*)d_in[3];
  const float* bk    = (const float*)d_in[4];
  const float* wv    = (const float*)d_in[5];
  const float* bv    = (const float*)d_in[6];
  const float* wo    = (const float*)d_in[7];
  const float* bo    = (const float*)d_in[8];
  const float* gamma = (const float*)d_in[9];
  const float* beta  = (const float*)d_in[10];

  char* ws = (char*)d_ws;
  unsigned short* xn   = (unsigned short*)(ws);              //  8,388,608 B
  unsigned short* wqkv = (unsigned short*)(ws + 8388608);    //  1,572,864 B
  unsigned short* wob  = (unsigned short*)(ws + 9961472);    //    524,288 B
  unsigned short* qb   = (unsigned short*)(ws + 10485760);   //  8,388,608 B
  unsigned short* Kp   = (unsigned short*)(ws + 18874368);   //  8,388,608 B (packed)
  unsigned short* Vp   = (unsigned short*)(ws + 27262976);   //  8,388,608 B (packed)
  unsigned short* ctx  = (unsigned short*)(ws + 35651584);   //  8,388,608 B

  float* out  = (float*)d_out;
  float* attn = (float*)d_out + 4194304;

  ln_kernel<<<8192, 256, 0, stream>>>(x, gamma, beta, xn);
  cast_w_kernel<<<1024, 256, 0, stream>>>(wq, wk, wv, wo, wqkv, wob);
  qkv_gemm<<<dim3(64, 12), 256, 0, stream>>>(xn, wqkv, bq, bk, bv, qb, Kp, Vp);
  attn_kernel<<<512, 256, 0, stream>>>(qb, Kp, Vp, attn, ctx);
  out_gemm<<<dim3(64, 8), 256, 0, stream>>>(ctx, wob, bo, x, out);
}

// Round 11
// 198.273 us; speedup vs baseline: 1.0560x; 1.0037x over previous
//
#include <hip/hip_runtime.h>

#define B_   4
#define H_   8
#define M_   2048
#define D_   512
#define DH_  64

typedef short  bf16x8 __attribute__((ext_vector_type(8)));
typedef short  bf16x4 __attribute__((ext_vector_type(4)));
typedef float  f32x4  __attribute__((ext_vector_type(4)));
typedef unsigned short u16x4 __attribute__((ext_vector_type(4)));
typedef unsigned int   u32x2 __attribute__((ext_vector_type(2)));

#define EXPC 0.18033688011112042f   /* log2(e)/8 : exp(s/8) == exp2(s*EXPC) */

static __device__ __forceinline__ unsigned short f2bf(float f) {
  unsigned u = __float_as_uint(f);
  u += 0x7fffu + ((u >> 16) & 1u);
  return (unsigned short)(u >> 16);
}

// one instruction: [bf16(lo), bf16(hi)] packed into a u32 (RNE)
static __device__ __forceinline__ unsigned cvtpk(float lo, float hi) {
  unsigned r;
  asm("v_cvt_pk_bf16_f32 %0, %1, %2" : "=v"(r) : "v"(lo), "v"(hi));
  return r;
}

// PV matrix op: D = A(4 bf16, d-rows) x B(4 bf16, n-k) + C. ISA cdna4 §10.
static __device__ __forceinline__ f32x4 mfma16(bf16x4 a, bf16x4 b, f32x4 c) {
  asm("v_mfma_f32_16x16x16_bf16 %0, %1, %2, %0" : "+v"(c) : "v"(a), "v"(b));
  return c;
}

static __device__ __forceinline__ int swz128(int row, int byteoff) {
  return row * 128 + (byteoff ^ ((row & 7) << 4));
}

// async global->LDS, 16B per lane, LDS dest = wave-uniform base + lane*16
static __device__ __forceinline__ void glds16(const void* g, void* l) {
  __builtin_amdgcn_global_load_lds(
      (const __attribute__((address_space(1))) unsigned*)g,
      (__attribute__((address_space(3))) unsigned*)l, 16, 0, 0);
}

// stage a 128-row x 128-byte tile (16KB) into LDS in swz128 layout
static __device__ __forceinline__ void stage_tile(
    const char* g0, size_t rstride, char* lds, int t) {
  const int r0 = t >> 3, c0 = t & 7;
  const char* src = g0 + (size_t)r0 * rstride + ((c0 ^ (r0 & 7)) << 4);
  char* dst = lds + ((t & 192) << 4);
  #pragma unroll
  for (int c = 0; c < 4; ++c)
    glds16(src + (size_t)c * 32 * rstride, dst + c * 4096);
}

// stage a 64-row x 128-byte tile (8KB) into LDS in swz128 layout
static __device__ __forceinline__ void stage64(
    const char* g0, size_t rstride, char* lds, int t) {
  #pragma unroll
  for (int c = 0; c < 2; ++c) {
    int s = c * 256 + t;
    int row = s >> 3, ch = s & 7;
    const char* src = g0 + (size_t)row * rstride + ((ch ^ (row & 7)) << 4);
    glds16(src, lds + c * 4096 + ((t & 192) << 4));
  }
}

// ---------------- LayerNorm -> bf16 ----------------
__global__ __launch_bounds__(256) void ln_kernel(
    const float* __restrict__ x, const float* __restrict__ gamma,
    const float* __restrict__ beta, unsigned short* __restrict__ xn)
{
  int row = blockIdx.x;
  int t = threadIdx.x;
  const float* xr = x + (size_t)row * D_;
  float v0 = xr[t], v1 = xr[t + 256];
  float s = v0 + v1, ss = v0 * v0 + v1 * v1;
  #pragma unroll
  for (int m = 1; m < 64; m <<= 1) {
    s  += __shfl_xor(s, m);
    ss += __shfl_xor(ss, m);
  }
  __shared__ float red[8];
  int wid = t >> 6;
  if ((t & 63) == 0) { red[wid] = s; red[wid + 4] = ss; }
  __syncthreads();
  s  = red[0] + red[1] + red[2] + red[3];
  ss = red[4] + red[5] + red[6] + red[7];
  float mu  = s * (1.0f / D_);
  float var = ss * (1.0f / D_) - mu * mu;
  float rstd = rsqrtf(var + 1e-5f);
  unsigned short* o = xn + (size_t)row * D_;
  o[t]       = f2bf((v0 - mu) * rstd * gamma[t]       + beta[t]);
  o[t + 256] = f2bf((v1 - mu) * rstd * gamma[t + 256] + beta[t + 256]);
}

// ---------------- weight casts ----------------
__global__ __launch_bounds__(256) void cast_w_kernel(
    const float* __restrict__ wq, const float* __restrict__ wk,
    const float* __restrict__ wv, const float* __restrict__ wo,
    unsigned short* __restrict__ wqkv, unsigned short* __restrict__ wob)
{
  int i = blockIdx.x * 256 + threadIdx.x;   // 262144 total
  wqkv[i]          = f2bf(wq[i]);
  wqkv[i + 262144] = f2bf(wk[i]);
  wqkv[i + 524288] = f2bf(wv[i]);
  wob[i]           = f2bf(wo[i]);
}

// ---------------- QKV GEMM: q row-major, K/V in MFMA-fragment-packed layout -
__global__ __launch_bounds__(256) void qkv_gemm(
    const unsigned short* __restrict__ xn,
    const unsigned short* __restrict__ wqkv,
    const float* __restrict__ bq, const float* __restrict__ bk,
    const float* __restrict__ bv,
    unsigned short* __restrict__ q, unsigned short* __restrict__ Kp,
    unsigned short* __restrict__ Vp)
{
  __shared__ __align__(16) char As[128 * 128];
  __shared__ __align__(16) char Bs[128 * 128];
  const int m0 = blockIdx.x * 128;
  const int n0 = blockIdx.y * 128;
  const int t = threadIdx.x, wid = t >> 6, lane = t & 63;
  const int wr = (wid >> 1) * 64, wc = (wid & 1) * 64;
  const int cl = lane & 15, rg = lane >> 4;
  const f32x4 z4 = {0.f, 0.f, 0.f, 0.f};
  const bool isv = (n0 >= 1024);

  const char* agb = (const char*)xn   + (size_t)m0 * 1024;
  const char* bgb = (const char*)wqkv + (size_t)n0 * 1024;

  f32x4 acc[4][4];
  #pragma unroll
  for (int i = 0; i < 4; ++i)
    #pragma unroll
    for (int j = 0; j < 4; ++j) acc[i][j] = z4;

  for (int k0 = 0; k0 < 512; k0 += 64) {
    __syncthreads();
    stage_tile(agb + k0 * 2, 1024, As, t);
    stage_tile(bgb + k0 * 2, 1024, Bs, t);
    __syncthreads();
    #pragma unroll
    for (int ks = 0; ks < 2; ++ks) {
      int koff = ks * 64 + rg * 16;
      bf16x8 af[4], bfr[4];
      #pragma unroll
      for (int i = 0; i < 4; ++i)
        af[i] = *(const bf16x8*)(As + swz128(wr + i * 16 + cl, koff));
      #pragma unroll
      for (int j = 0; j < 4; ++j)
        bfr[j] = *(const bf16x8*)(Bs + swz128(wc + j * 16 + cl, koff));
      if (isv) {
        #pragma unroll
        for (int i = 0; i < 4; ++i)
          #pragma unroll
          for (int j = 0; j < 4; ++j)
            acc[i][j] = __builtin_amdgcn_mfma_f32_16x16x32_bf16(af[i], bfr[j], acc[i][j], 0, 0, 0);
      } else {
        #pragma unroll
        for (int j = 0; j < 4; ++j)
          #pragma unroll
          for (int i = 0; i < 4; ++i)
            acc[j][i] = __builtin_amdgcn_mfma_f32_16x16x32_bf16(bfr[j], af[i], acc[j][i], 0, 0, 0);
      }
    }
  }

  if (isv) {
    #pragma unroll
    for (int j = 0; j < 4; ++j) {
      int n = n0 + wc + j * 16 + cl;
      int nn = n & 511;
      int h = nn >> 6, dh = nn & 63;
      int jd = dh >> 4, cld = dh & 15;
      float bias = bv[nn];
      #pragma unroll
      for (int i = 0; i < 4; ++i) {
        int mrow = m0 + wr + i * 16 + rg * 4;
        int b = mrow >> 11, mm = mrow & 2047;
        int nt = mm >> 6, nl = mm & 63;
        int jp = nl >> 5, half = (nl >> 4) & 1, rgv = (nl >> 2) & 3;
        u32x2 u;
        u[0] = cvtpk(acc[i][j][0] + bias, acc[i][j][1] + bias);
        u[1] = cvtpk(acc[i][j][2] + bias, acc[i][j][3] + bias);
        size_t off = ((((size_t)(b * H_ + h) * 32 + nt) * 4 + jd) * 2 + jp) * 512
                   + (rgv * 16 + cld) * 8 + half * 4;
        *(u16x4*)(Vp + off) = __builtin_bit_cast(u16x4, u);
      }
    }
  } else {
    const int mat = n0 >> 9;                  // 0: q, 1: k
    #pragma unroll
    for (int j = 0; j < 4; ++j) {
      int nn0 = ((n0 + wc) & 511) + j * 16 + rg * 4;
      int h = nn0 >> 6, dh = nn0 & 63;
      f32x4 b4 = *(const f32x4*)((mat ? bk : bq) + nn0);
      #pragma unroll
      for (int i = 0; i < 4; ++i) {
        int mrow = m0 + wr + i * 16 + cl;
        int b = mrow >> 11, mm = mrow & 2047;
        u32x2 u;
        u[0] = cvtpk(acc[j][i][0] + b4[0], acc[j][i][1] + b4[1]);
        u[1] = cvtpk(acc[j][i][2] + b4[2], acc[j][i][3] + b4[3]);
        if (mat == 0) {
          *(u16x4*)(q + ((size_t)(b * H_ + h) * M_ + mm) * DH_ + dh) =
              __builtin_bit_cast(u16x4, u);
        } else {
          int ks = dh >> 5, rgk = (dh >> 3) & 3, e0 = dh & 7;   // e0 in {0,4}
          size_t off = ((((size_t)(b * H_ + h) * 32 + (mm >> 6)) * 4 + ((mm >> 4) & 3)) * 2 + ks) * 512
                     + (rgk * 16 + (mm & 15)) * 8 + e0;
          *(u16x4*)(Kp + off) = __builtin_bit_cast(u16x4, u);
        }
      }
    }
  }
}

// ---------------- Attention v11: producer/consumer wave specialization ------
// grid 256 (XCD-local bh); block 512 thr = 8 waves.
// waves 0-3 (P): psum of unit u+1.  waves 4-7 (C): pass2 of unit u (stores).
// 5-stage pipeline over 4 units of 64 rows; rv handoff via LDS double buffer.
__global__ __launch_bounds__(512, 4) void attn_kernel(
    const unsigned short* __restrict__ q,
    const unsigned short* __restrict__ Kp,
    const unsigned short* __restrict__ Vp,
    float* __restrict__ attn,
    unsigned short* __restrict__ ctx)
{
  __shared__ __align__(16) char Ps[8][2048];
  __shared__ float rvs[2][64];

  const int bid = blockIdx.x;
  const int bh   = (bid & 7) * 4 + (bid >> 6);     // 4 bh per XCD
  const int ublk = (bid >> 3) & 7;                 // 8 blocks per bh
  const int u0   = ublk * 4;                       // 4 units of 64 rows
  const int t = threadIdx.x, wid = t >> 6, lane = t & 63;
  const int grp = wid >> 2, ws = wid & 3;
  const int wr = ws * 16, cl = lane & 15, rg = lane >> 4;
  const f32x4 z4 = {0.f, 0.f, 0.f, 0.f};

  const char* qb = (const char*)(q + (size_t)bh * M_ * DH_);
  const unsigned short* kpb = Kp + (size_t)bh * 131072;   // 256 KB per bh
  const unsigned short* vpb = Vp + (size_t)bh * 131072;
  float* ab = attn + (size_t)bh * M_ * M_;
  const int b = bh >> 3, h = bh & 7;

  const int srow = lane >> 4;          // attn-store row-in-group 0..3
  const int sch  = lane & 15;          // attn-store 16B-chunk 0..15

  for (int s = 0; s <= 4; ++s) {
    if (grp == 0 && s < 4) {
      // -------- producer: psum(unit u0+s) --------
      const int u = u0 + s;
      const int m_g = u * 64 + wr + cl;
      bf16x8 qf[2];
      #pragma unroll
      for (int ks = 0; ks < 2; ++ks)
        qf[ks] = *(const bf16x8*)(qb + (size_t)m_g * 128 + ks * 64 + rg * 16);
      float psum = 0.f;
      for (int nt = 0; nt < 32; ++nt) {
        const unsigned short* kch = kpb + (size_t)nt * 4096;
        f32x4 sj[4];
        #pragma unroll
        for (int j = 0; j < 4; ++j) sj[j] = z4;
        #pragma unroll
        for (int ks = 0; ks < 2; ++ks)
          #pragma unroll
          for (int j = 0; j < 4; ++j) {
            bf16x8 kf = *(const bf16x8*)(kch + (j * 2 + ks) * 512 + lane * 8);
            sj[j] = __builtin_amdgcn_mfma_f32_16x16x32_bf16(kf, qf[ks], sj[j], 0, 0, 0);
          }
        if (nt == u) {
          #pragma unroll
          for (int j = 0; j < 4; ++j)
            #pragma unroll
            for (int r = 0; r < 4; ++r) {
              int n_g = nt * 64 + j * 16 + rg * 4 + r;
              float p = __builtin_amdgcn_exp2f(sj[j][r] * EXPC);
              psum += (n_g == m_g) ? 0.f : p;
            }
        } else {
          #pragma unroll
          for (int j = 0; j < 4; ++j)
            #pragma unroll
            for (int r = 0; r < 4; ++r)
              psum += __builtin_amdgcn_exp2f(sj[j][r] * EXPC);
        }
      }
      psum += __shfl_xor(psum, 16);
      psum += __shfl_xor(psum, 32);
      if (lane < 16) rvs[s & 1][wr + cl] = 1.0f / psum;
    } else if (grp == 1 && s > 0) {
      // -------- consumer: pass2(unit u0+s-1), stores streaming --------
      const int u = u0 + s - 1;
      const int m_g = u * 64 + wr + cl;
      const float rv = rvs[(s - 1) & 1][wr + cl];
      bf16x8 qf[2];
      #pragma unroll
      for (int ks = 0; ks < 2; ++ks)
        qf[ks] = *(const bf16x8*)(qb + (size_t)m_g * 128 + ks * 64 + rg * 16);
      f32x4 oc[4];
      #pragma unroll
      for (int j = 0; j < 4; ++j) oc[j] = z4;
      asm volatile("s_nop 7" :::);     // VALU init -> asm MFMA srcC guard

      for (int nt = 0; nt < 32; ++nt) {
        const unsigned short* kch = kpb + (size_t)nt * 4096;
        const unsigned short* vch = vpb + (size_t)nt * 4096;
        f32x4 sj[4];
        #pragma unroll
        for (int j = 0; j < 4; ++j) sj[j] = z4;
        #pragma unroll
        for (int ks = 0; ks < 2; ++ks)
          #pragma unroll
          for (int j = 0; j < 4; ++j) {
            bf16x8 kf = *(const bf16x8*)(kch + (j * 2 + ks) * 512 + lane * 8);
            sj[j] = __builtin_amdgcn_mfma_f32_16x16x32_bf16(kf, qf[ks], sj[j], 0, 0, 0);
          }
        const bool dtile = (nt == u);
        bf16x4 pb[4];
        #pragma unroll
        for (int j = 0; j < 4; ++j) {
          f32x4 pv;
          #pragma unroll
          for (int r = 0; r < 4; ++r) {
            int n_g = nt * 64 + j * 16 + rg * 4 + r;
            float p = __builtin_amdgcn_exp2f(sj[j][r] * EXPC) * rv;
            pv[r] = (dtile && n_g == m_g) ? 0.f : p;
          }
          u32x2 uu;
          uu[0] = cvtpk(pv[0], pv[1]);
          uu[1] = cvtpk(pv[2], pv[3]);
          pb[j] = __builtin_bit_cast(bf16x4, uu);
          *(u32x2*)(Ps[wid] + swz128(cl, j * 32 + rg * 8)) = uu;  // per-wave
        }
        // attn store: dense 4 rows x 256B, NT, stays in flight
        {
          float* abase = ab + ((size_t)(u * 64 + wr + srow)) * M_ + nt * 64 + sch * 4;
          #pragma unroll
          for (int it = 0; it < 4; ++it) {
            u16x4 pu = *(const u16x4*)(Ps[wid] + swz128(it * 4 + srow, sch * 8));
            f32x4 pv;
            #pragma unroll
            for (int r = 0; r < 4; ++r) pv[r] = __uint_as_float((unsigned)pu[r] << 16);
            __builtin_nontemporal_store(pv, (f32x4*)(abase + (size_t)it * 4 * M_));
          }
        }
        // PV
        #pragma unroll
        for (int jp = 0; jp < 2; ++jp)
          #pragma unroll
          for (int jd = 0; jd < 4; ++jd) {
            bf16x8 w = *(const bf16x8*)(vch + (jd * 2 + jp) * 512 + lane * 8);
            bf16x4 vlo = __builtin_shufflevector(w, w, 0, 1, 2, 3);
            bf16x4 vhi = __builtin_shufflevector(w, w, 4, 5, 6, 7);
            oc[jd] = mfma16(vlo, pb[jp * 2],     oc[jd]);
            oc[jd] = mfma16(vhi, pb[jp * 2 + 1], oc[jd]);
          }
      }
      asm volatile("s_nop 7\n\ts_nop 7" :::);   // asm MFMA -> VALU read guard
      unsigned short* crow = ctx + ((size_t)b * M_ + m_g) * D_ + h * DH_ + rg * 4;
      #pragma unroll
      for (int jd = 0; jd < 4; ++jd) {
        u32x2 uu;
        uu[0] = cvtpk(oc[jd][0], oc[jd][1]);
        uu[1] = cvtpk(oc[jd][2], oc[jd][3]);
        *(u32x2*)(crow + jd * 16) = uu;
      }
    }
    __syncthreads();
  }
}

// ---------------- out = ctx @ wo^T + bo + x (128x64 tiles, 2 blocks/CU) -----
__global__ __launch_bounds__(256) void out_gemm(
    const unsigned short* __restrict__ ctxb,
    const unsigned short* __restrict__ wob,
    const float* __restrict__ bo,
    const float* __restrict__ x,
    float* __restrict__ out)
{
  __shared__ __align__(16) char As[128 * 128];
  __shared__ __align__(16) char Bs[64 * 128];
  const int m0 = blockIdx.x * 128;
  const int n0 = blockIdx.y * 64;
  const int t = threadIdx.x, wid = t >> 6, lane = t & 63;
  const int wr = (wid >> 1) * 64, wc = (wid & 1) * 32;
  const int cl = lane & 15, rg = lane >> 4;
  const f32x4 z4 = {0.f, 0.f, 0.f, 0.f};

  const char* agb = (const char*)ctxb + (size_t)m0 * 1024;
  const char* bgb = (const char*)wob  + (size_t)n0 * 1024;

  f32x4 acc[2][4];   // [j: n frag][i: m frag], row=n, col=m
  #pragma unroll
  for (int j = 0; j < 2; ++j)
    #pragma unroll
    for (int i = 0; i < 4; ++i) acc[j][i] = z4;

  for (int k0 = 0; k0 < 512; k0 += 64) {
    __syncthreads();
    stage_tile(agb + k0 * 2, 1024, As, t);
    stage64(bgb + k0 * 2, 1024, Bs, t);
    __syncthreads();
    #pragma unroll
    for (int ks = 0; ks < 2; ++ks) {
      int koff = ks * 64 + rg * 16;
      bf16x8 af[4], bfr[2];
      #pragma unroll
      for (int i = 0; i < 4; ++i)
        af[i] = *(const bf16x8*)(As + swz128(wr + i * 16 + cl, koff));
      #pragma unroll
      for (int j = 0; j < 2; ++j)
        bfr[j] = *(const bf16x8*)(Bs + swz128(wc + j * 16 + cl, koff));
      #pragma unroll
      for (int j = 0; j < 2; ++j)
        #pragma unroll
        for (int i = 0; i < 4; ++i)
          acc[j][i] = __builtin_amdgcn_mfma_f32_16x16x32_bf16(bfr[j], af[i], acc[j][i], 0, 0, 0);
    }
  }

  #pragma unroll
  for (int j = 0; j < 2; ++j) {
    int nb = n0 + wc + j * 16 + rg * 4;
    f32x4 bo4 = *(const f32x4*)(bo + nb);
    #pragma unroll
    for (int i = 0; i < 4; ++i) {
      int m = m0 + wr + i * 16 + cl;
      f32x4 x4 = *(const f32x4*)(x + (size_t)m * 512 + nb);
      f32x4 o;
      #pragma unroll
      for (int r = 0; r < 4; ++r) o[r] = acc[j][i][r] + bo4[r] + x4[r];
      *(f32x4*)(out + (size_t)m * 512 + nb) = o;
    }
  }
}

extern "C" void kernel_launch(void* const* d_in, const int* in_sizes, int n_in,
                              void* d_out, int out_size, void* d_ws, size_t ws_size,
                              hipStream_t stream) {
  const float* x     = (const float*)d_in[0];
  const float* wq    = (const float*)d_in[1];
  const float* bq    = (const float*)d_in[2];
  const float* wk    = (const float*)d_in[3];
  const float* bk    = (const float*)d_in[4];
  const float* wv    = (const float*)d_in[5];
  const float* bv    = (const float*)d_in[6];
  const float* wo    = (const float*)d_in[7];
  const float* bo    = (const float*)d_in[8];
  const float* gamma = (const float*)d_in[9];
  const float* beta  = (const float*)d_in[10];

  char* ws = (char*)d_ws;
  unsigned short* xn   = (unsigned short*)(ws);              //  8,388,608 B
  unsigned short* wqkv = (unsigned short*)(ws + 8388608);    //  1,572,864 B
  unsigned short* wob  = (unsigned short*)(ws + 9961472);    //    524,288 B
  unsigned short* qb   = (unsigned short*)(ws + 10485760);   //  8,388,608 B
  unsigned short* Kp   = (unsigned short*)(ws + 18874368);   //  8,388,608 B (packed)
  unsigned short* Vp   = (unsigned short*)(ws + 27262976);   //  8,388,608 B (packed)
  unsigned short* ctx  = (unsigned short*)(ws + 35651584);   //  8,388,608 B

  float* out  = (float*)d_out;
  float* attn = (float*)d_out + 4194304;

  ln_kernel<<<8192, 256, 0, stream>>>(x, gamma, beta, xn);
  cast_w_kernel<<<1024, 256, 0, stream>>>(wq, wk, wv, wo, wqkv, wob);
  qkv_gemm<<<dim3(64, 12), 256, 0, stream>>>(xn, wqkv, bq, bk, bv, qb, Kp, Vp);
  attn_kernel<<<256, 512, 0, stream>>>(qb, Kp, Vp, attn, ctx);
  out_gemm<<<dim3(64, 8), 256, 0, stream>>>(ctx, wob, bo, x, out);
}